// Round 2
// baseline (249.748 us; speedup 1.0000x reference)
//
#include <hip/hip_runtime.h>

#define FDIM 1024
#define NLAYERS 4

typedef float v4f __attribute__((ext_vector_type(4)));

// One wave (64 lanes) per row; 4 waves per 256-thread block.
// Each lane holds 16 row elements as 4x v4f in registers (x0 and xi).
// Per layer: 16 FMAs -> 6-step wave shuffle reduce -> register update.
// x/out use non-temporal (nt) accesses: streamed once, keep caches free
// for the W/B vectors (32 KB, re-read by every wave).
__global__ __launch_bounds__(256) void cross_net_kernel(
    const float* __restrict__ x, const float* __restrict__ Ws,
    const float* __restrict__ Bs, float* __restrict__ out, int nrows) {
  const int wave = threadIdx.x >> 6;
  const int lane = threadIdx.x & 63;
  const int row = blockIdx.x * 4 + wave;
  if (row >= nrows) return;

  const float* xr = x + (size_t)row * FDIM;
  v4f x0[4], xi[4];
#pragma unroll
  for (int c = 0; c < 4; ++c) {
    // lane-coalesced: lanes cover a contiguous 1 KiB segment per chunk
    x0[c] = __builtin_nontemporal_load(
        reinterpret_cast<const v4f*>(xr + c * 256 + lane * 4));
    xi[c] = x0[c];
  }

#pragma unroll
  for (int i = 0; i < NLAYERS; ++i) {
    const float* W = Ws + i * FDIM;
    const float* B = Bs + i * FDIM;
    v4f w[4], b[4];
#pragma unroll
    for (int c = 0; c < 4; ++c) {
      w[c] = *reinterpret_cast<const v4f*>(W + c * 256 + lane * 4);
      b[c] = *reinterpret_cast<const v4f*>(B + c * 256 + lane * 4);
    }
    // partial dot over this lane's 16 elements
    float s = 0.f;
#pragma unroll
    for (int c = 0; c < 4; ++c) {
      s = fmaf(xi[c].x, w[c].x, s);
      s = fmaf(xi[c].y, w[c].y, s);
      s = fmaf(xi[c].z, w[c].z, s);
      s = fmaf(xi[c].w, w[c].w, s);
    }
    // 64-lane butterfly reduce (wave=64 on CDNA)
#pragma unroll
    for (int off = 32; off > 0; off >>= 1) s += __shfl_xor(s, off, 64);
    // xi = x0 * s + B + xi
#pragma unroll
    for (int c = 0; c < 4; ++c) {
      xi[c].x = fmaf(x0[c].x, s, b[c].x + xi[c].x);
      xi[c].y = fmaf(x0[c].y, s, b[c].y + xi[c].y);
      xi[c].z = fmaf(x0[c].z, s, b[c].z + xi[c].z);
      xi[c].w = fmaf(x0[c].w, s, b[c].w + xi[c].w);
    }
  }

  float* outr = out + (size_t)row * FDIM;
#pragma unroll
  for (int c = 0; c < 4; ++c)
    __builtin_nontemporal_store(
        xi[c], reinterpret_cast<v4f*>(outr + c * 256 + lane * 4));
}

extern "C" void kernel_launch(void* const* d_in, const int* in_sizes, int n_in,
                              void* d_out, int out_size, void* d_ws, size_t ws_size,
                              hipStream_t stream) {
  const float* x  = (const float*)d_in[0];
  const float* Ws = (const float*)d_in[1];
  const float* Bs = (const float*)d_in[2];
  float* out = (float*)d_out;
  const int nrows = in_sizes[0] / FDIM;  // 32768
  const int grid = (nrows + 3) / 4;      // 4 rows (waves) per block
  hipLaunchKernelGGL(cross_net_kernel, dim3(grid), dim3(256), 0, stream,
                     x, Ws, Bs, out, nrows);
}

// Round 5
// 237.943 us; speedup vs baseline: 1.0496x; 1.0496x over previous
//
#include <hip/hip_runtime.h>

#define FDIM 1024
#define NLAYERS 4

typedef float v4f __attribute__((ext_vector_type(4)));

// ---------------------------------------------------------------------------
// Algebraic form of the cross layer:
//   x_{i+1} = x0*s_i + B_i + x_i,  s_i = dot(x_i, W_i)
// =>  x_i = alpha_i * x0 + beta_i,   beta_i = sum_{k<i} B_k  (row-independent)
//     s_i = alpha_i * d_i + e_i,     d_i = dot(x0, W_i)  (per-row)
//                                    e_i = dot(beta_i, W_i)  (row-independent)
//     alpha_{i+1} = alpha_i + s_i,   alpha_0 = 1
//   out = alpha_4 * x0 + SB,         SB = beta_4 = B0+B1+B2+B3
// ---------------------------------------------------------------------------

// Pre-kernel: one block computes e1,e2,e3 (e0==0) and SB[1024] into d_ws.
// ws layout: ws[0..2] = e1,e2,e3 ; ws[16..16+1023] = SB.
__global__ __launch_bounds__(256) void cross_net_pre(
    const float* __restrict__ Ws, const float* __restrict__ Bs,
    float* __restrict__ ws) {
  const int t = threadIdx.x;
  __shared__ float red[3][256];
  float e1 = 0.f, e2 = 0.f, e3 = 0.f;
#pragma unroll
  for (int c = 0; c < 4; ++c) {
    const int f = c * 256 + t;
    const float B0 = Bs[0 * FDIM + f], B1 = Bs[1 * FDIM + f];
    const float B2 = Bs[2 * FDIM + f], B3 = Bs[3 * FDIM + f];
    const float W1 = Ws[1 * FDIM + f], W2 = Ws[2 * FDIM + f];
    const float W3 = Ws[3 * FDIM + f];
    const float beta1 = B0;
    const float beta2 = beta1 + B1;
    const float beta3 = beta2 + B2;
    e1 = fmaf(beta1, W1, e1);
    e2 = fmaf(beta2, W2, e2);
    e3 = fmaf(beta3, W3, e3);
    ws[16 + f] = beta3 + B3;  // SB
  }
  red[0][t] = e1; red[1][t] = e2; red[2][t] = e3;
  __syncthreads();
#pragma unroll
  for (int s = 128; s > 0; s >>= 1) {
    if (t < s) {
      red[0][t] += red[0][t + s];
      red[1][t] += red[1][t + s];
      red[2][t] += red[2][t + s];
    }
    __syncthreads();
  }
  if (t == 0) { ws[0] = red[0][0]; ws[1] = red[1][0]; ws[2] = red[2][0]; }
}

// Main kernel: one wave per row. One pass over x0 computes d0..d3, one
// 4-wide butterfly reduce, scalar alpha recursion, then out = a*x0 + SB.
__global__ __launch_bounds__(256) void cross_net_main(
    const float* __restrict__ x, const float* __restrict__ Ws,
    const float* __restrict__ ws, float* __restrict__ out, int nrows) {
  const int wave = threadIdx.x >> 6;
  const int lane = threadIdx.x & 63;
  const int row = blockIdx.x * 4 + wave;
  if (row >= nrows) return;

  const float* xr = x + (size_t)row * FDIM;
  v4f x0[4];
#pragma unroll
  for (int c = 0; c < 4; ++c)
    x0[c] = __builtin_nontemporal_load(
        reinterpret_cast<const v4f*>(xr + c * 256 + lane * 4));

  // d_j = partial dot(x0, W_j) over this lane's 16 elements
  float d[4];
#pragma unroll
  for (int j = 0; j < NLAYERS; ++j) {
    const float* W = Ws + j * FDIM;
    float s = 0.f;
#pragma unroll
    for (int c = 0; c < 4; ++c) {
      const v4f w = *reinterpret_cast<const v4f*>(W + c * 256 + lane * 4);
      s = fmaf(x0[c].x, w.x, s);
      s = fmaf(x0[c].y, w.y, s);
      s = fmaf(x0[c].z, w.z, s);
      s = fmaf(x0[c].w, w.w, s);
    }
    d[j] = s;
  }
  // one 64-lane butterfly reduce, 4-wide ILP
#pragma unroll
  for (int off = 32; off > 0; off >>= 1) {
#pragma unroll
    for (int j = 0; j < NLAYERS; ++j) d[j] += __shfl_xor(d[j], off, 64);
  }

  // scalar alpha recursion (e0 == 0)
  const float e1 = ws[0], e2 = ws[1], e3 = ws[2];
  float a = 1.f + d[0];
  a += fmaf(a, d[1], e1);
  a += fmaf(a, d[2], e2);
  a += fmaf(a, d[3], e3);

  const float* SB = ws + 16;
  float* outr = out + (size_t)row * FDIM;
#pragma unroll
  for (int c = 0; c < 4; ++c) {
    const v4f sb = *reinterpret_cast<const v4f*>(SB + c * 256 + lane * 4);
    v4f r;
    r.x = fmaf(a, x0[c].x, sb.x);
    r.y = fmaf(a, x0[c].y, sb.y);
    r.z = fmaf(a, x0[c].z, sb.z);
    r.w = fmaf(a, x0[c].w, sb.w);
    __builtin_nontemporal_store(
        r, reinterpret_cast<v4f*>(outr + c * 256 + lane * 4));
  }
}

extern "C" void kernel_launch(void* const* d_in, const int* in_sizes, int n_in,
                              void* d_out, int out_size, void* d_ws, size_t ws_size,
                              hipStream_t stream) {
  const float* x  = (const float*)d_in[0];
  const float* Ws = (const float*)d_in[1];
  const float* Bs = (const float*)d_in[2];
  float* out = (float*)d_out;
  float* ws  = (float*)d_ws;
  const int nrows = in_sizes[0] / FDIM;  // 32768
  hipLaunchKernelGGL(cross_net_pre, dim3(1), dim3(256), 0, stream, Ws, Bs, ws);
  const int grid = (nrows + 3) / 4;  // 4 rows (waves) per block
  hipLaunchKernelGGL(cross_net_main, dim3(grid), dim3(256), 0, stream,
                     x, Ws, ws, out, nrows);
}